// Round 1
// 415.760 us; speedup vs baseline: 1.0730x; 1.0730x over previous
//
#include <hip/hip_runtime.h>
#include <stdint.h>
#include <math.h>

// Problem constants (B,T,J,D) = (64, 2048, 128, 512)
#define BB 64
#define TT 2048
#define JJ 128
#define DD 512
#define BK 32    // K chunk per step (one 16x16x32 MFMA K)

typedef short short8 __attribute__((ext_vector_type(8)));
typedef float f32x4 __attribute__((ext_vector_type(4)));

typedef const __attribute__((address_space(1))) uint32_t glb_u32;
typedef __attribute__((address_space(3))) uint32_t lds_u32;

// async global->LDS DMA, 16B per lane; LDS dest = wave-uniform base + lane*16
__device__ __forceinline__ void dma16(const void* g, void* l) {
  __builtin_amdgcn_global_load_lds((glb_u32*)g, (lds_u32*)l, 16, 0, 0);
}

__device__ inline unsigned pk_hi(float a, float b) {
  // (hi16(a)) | (hi16(b) << 16) -- bf16 truncation pack of 2 fp32
  return __builtin_amdgcn_perm(__float_as_uint(b), __float_as_uint(a), 0x07060302u);
}
__device__ inline float truncbf(float x) {
  return __uint_as_float(__float_as_uint(x) & 0xFFFF0000u);
}
// 8 fp32 (two float4) -> hi chunk (8 bf16) + lo chunk (8 bf16)
__device__ inline void pack8(float4 a, float4 b, uint4& h, uint4& l) {
  h = make_uint4(pk_hi(a.x, a.y), pk_hi(a.z, a.w), pk_hi(b.x, b.y), pk_hi(b.z, b.w));
  float l0 = a.x - truncbf(a.x), l1 = a.y - truncbf(a.y);
  float l2 = a.z - truncbf(a.z), l3 = a.w - truncbf(a.w);
  float l4 = b.x - truncbf(b.x), l5 = b.y - truncbf(b.y);
  float l6 = b.z - truncbf(b.z), l7 = b.w - truncbf(b.w);
  l = make_uint4(pk_hi(l0, l1), pk_hi(l2, l3), pk_hi(l4, l5), pk_hi(l6, l7));
}
__device__ inline short8 bc8(uint4 u) { return __builtin_bit_cast(short8, u); }

// ---------------- Kernel A0: pre-pack Q*w into hi/lo bf16 tile images --------
// Qhi/Qlo layout: [b][ks (16)][slot (512 uint4)], slot = j*4 + (c ^ ((j>>1)&3))
// i.e. exactly the byte image the GEMM wants in LDS (swizzle pre-baked).
__global__ __launch_bounds__(256)
void qpack_kernel(const float* __restrict__ Qm, const float* __restrict__ w,
                  uint4* __restrict__ Qhi, uint4* __restrict__ Qlo) {
  const int gid = blockIdx.x * 256 + threadIdx.x;  // 0 .. 524287
  const int c = gid & 3;
  const int ks = (gid >> 2) & 15;
  const int j = (gid >> 6) & 127;
  const int b = gid >> 13;
  const float* qp = Qm + (((size_t)b * JJ + j) * DD) + ks * BK + c * 8;
  const float* wp = w + ks * BK + c * 8;
  float4 a = *(const float4*)qp;
  float4 bq = *(const float4*)(qp + 4);
  float4 wa = *(const float4*)wp;
  float4 wb = *(const float4*)(wp + 4);
  a.x *= wa.x; a.y *= wa.y; a.z *= wa.z; a.w *= wa.w;
  bq.x *= wb.x; bq.y *= wb.y; bq.z *= wb.z; bq.w *= wb.w;
  uint4 h, l;
  pack8(a, bq, h, l);
  const int slot = j * 4 + (c ^ ((j >> 1) & 3));
  const size_t o = ((size_t)(b * 16 + ks)) * 512 + slot;
  Qhi[o] = h;
  Qlo[o] = l;
}

// ---------------- Kernel A: S[b][j][t] = sum_d (Q[b][j][d]*w[d]) * C[b][t][d]
// 128x128 tile, split-bf16 (hi/lo) 3-MFMA scheme, 16 K-steps of 32.
// All staging via global_load_lds DMA (deep in-flight queue, no VGPR roundtrip):
//   A: pre-packed bf16 hi/lo tile images (swizzle baked in by qpack_kernel)
//   C: raw fp32 rows, 16B-chunk XOR swizzle (sub ^ (row&7)) applied on the
//      per-lane GLOBAL source address (LDS dest stays linear), converted to
//      hi/lo bf16 at fragment-read time.
__global__ __launch_bounds__(256, 3)
void sim_gemm_mfma(const uint4* __restrict__ Qhi, const uint4* __restrict__ Qlo,
                   const float* __restrict__ Cm, float* __restrict__ S) {
  __shared__ uint4 Ah[512];   // 8 KB : 128 rows x 4 chunks (8 bf16 each)
  __shared__ uint4 Al[512];   // 8 KB
  __shared__ uint4 Cl[1024];  // 16 KB: 128 rows x 8 subs (4 fp32 each), swizzled

  const int tid = threadIdx.x;
  const int lane = tid & 63;
  const int wv = tid >> 6;

  // XCD-aware swizzle: 1024 blocks, 8 XCDs -> XCD x gets b in [x*8, x*8+8)
  // so each XCD's L2 only needs 8 b's of Qpk (2 MB < 4 MB).
  const int id = blockIdx.x;
  const int nid = (id & 7) * 128 + (id >> 3);
  const int b = nid >> 4;
  const int t0 = (nid & 15) * 128;

  // ---- DMA source/dest setup
  // A tile (per ks) = 512 uint4 verbatim from Qhi/Qlo; wave wv covers
  // [wv*128, wv*128+128) uint4 in 2 sweeps of 64.
  const uint4* qh_src = Qhi + (size_t)b * 8192 + wv * 128 + lane;
  const uint4* ql_src = Qlo + (size_t)b * 8192 + wv * 128 + lane;
  char* ah_dst = (char*)Ah + wv * 2048;
  char* al_dst = (char*)Al + wv * 2048;
  // C tile: wave wv covers rows [wv*32, wv*32+32) in 4 sweeps of 8 rows.
  // LDS linear pos (row, sub=lane&7) sources global chunk sub^(row&7);
  // row&7 == (lane>>3)&7 for every sweep.
  const int crow = wv * 32 + (lane >> 3);
  const int cch = (lane & 7) ^ ((lane >> 3) & 7);
  const float* c_src = Cm + ((size_t)b * TT + t0 + crow) * DD + cch * 4;
  char* cl_dst = (char*)Cl + wv * 4096;

  // ---- MFMA fragment assignment: 4 waves in 2x2 over 128x128
  const int wm = (wv & 1) * 64;
  const int wn = (wv >> 1) * 64;
  const int l15 = lane & 15;
  const int q = lane >> 4;
  const int fchunk = q ^ ((l15 >> 1) & 3);
  const int swl = l15 & 7;

  int aslot[4];
#pragma unroll
  for (int i = 0; i < 4; i++) aslot[i] = (wm + i * 16 + l15) * 4 + fchunk;

  f32x4 acc[4][4] = {};

  for (int ks = 0; ks < 16; ks++) {
    __syncthreads();  // previous iter's fragment reads complete
#pragma unroll
    for (int s = 0; s < 2; s++) {
      dma16(qh_src + ks * 512 + s * 64, ah_dst + s * 1024);
      dma16(ql_src + ks * 512 + s * 64, al_dst + s * 1024);
    }
#pragma unroll
    for (int s = 0; s < 4; s++) {
      dma16(c_src + (size_t)ks * BK + s * 8 * DD, cl_dst + s * 1024);
    }
    __syncthreads();  // compiler drains vmcnt(0) before barrier -> tiles visible

    // B fragments: read fp32 from LDS (swizzled subs), convert to hi/lo bf16
    short8 bh[4], bl[4];
#pragma unroll
    for (int ni = 0; ni < 4; ni++) {
      const int row = wn + ni * 16 + l15;
      float4 v0 = __builtin_bit_cast(float4, Cl[row * 8 + ((2 * q) ^ swl)]);
      float4 v1 = __builtin_bit_cast(float4, Cl[row * 8 + ((2 * q + 1) ^ swl)]);
      uint4 h, l;
      pack8(v0, v1, h, l);
      bh[ni] = bc8(h);
      bl[ni] = bc8(l);
    }
#pragma unroll
    for (int mi = 0; mi < 4; mi++) {
      short8 ah = bc8(Ah[aslot[mi]]);
      short8 al = bc8(Al[aslot[mi]]);
#pragma unroll
      for (int ni = 0; ni < 4; ni++) {
        acc[mi][ni] = __builtin_amdgcn_mfma_f32_16x16x32_bf16(ah, bh[ni], acc[mi][ni], 0, 0, 0);
        acc[mi][ni] = __builtin_amdgcn_mfma_f32_16x16x32_bf16(al, bh[ni], acc[mi][ni], 0, 0, 0);
        acc[mi][ni] = __builtin_amdgcn_mfma_f32_16x16x32_bf16(ah, bl[ni], acc[mi][ni], 0, 0, 0);
      }
    }
  }

  // epilogue: C/D layout col=lane&15, row=(lane>>4)*4+reg
#pragma unroll
  for (int mi = 0; mi < 4; mi++) {
#pragma unroll
    for (int ni = 0; ni < 4; ni++) {
      const int j = wm + mi * 16 + q * 4;
      const int t = t0 + wn + ni * 16 + l15;
      float* dst = S + ((size_t)b * JJ + j) * TT + t;
      dst[0 * TT] = acc[mi][ni][0];
      dst[1 * TT] = acc[mi][ni][1];
      dst[2 * TT] = acc[mi][ni][2];
      dst[3 * TT] = acc[mi][ni][3];
    }
  }
}

// ---------------- Kernel B: per-(b,j) softmax stats over valid t -------------
// Single pass: whole 2048-row in registers (8 floats/thread), masked max+sum.
__global__ __launch_bounds__(256)
void softmax_stats_kernel(const float* __restrict__ S, const int* __restrict__ qlen,
                          const int* __restrict__ clen, float* __restrict__ m_out,
                          float* __restrict__ r_out) {
  const int j = blockIdx.x;
  const int b = blockIdx.y;
  if (j >= qlen[b]) return;
  const int cl = clen[b];
  const int tid = threadIdx.x;
  const float4* row = (const float4*)(S + ((size_t)b * JJ + j) * TT);

  float4 v0 = row[tid];
  float4 v1 = row[tid + 256];
  const int t0 = tid * 4;
  const int t1 = (tid + 256) * 4;
  const float NEG = -3.4e38f;

  float m = NEG;
  m = fmaxf(m, (t0 + 0 < cl) ? v0.x : NEG);
  m = fmaxf(m, (t0 + 1 < cl) ? v0.y : NEG);
  m = fmaxf(m, (t0 + 2 < cl) ? v0.z : NEG);
  m = fmaxf(m, (t0 + 3 < cl) ? v0.w : NEG);
  m = fmaxf(m, (t1 + 0 < cl) ? v1.x : NEG);
  m = fmaxf(m, (t1 + 1 < cl) ? v1.y : NEG);
  m = fmaxf(m, (t1 + 2 < cl) ? v1.z : NEG);
  m = fmaxf(m, (t1 + 3 < cl) ? v1.w : NEG);

  __shared__ float red[8];
#pragma unroll
  for (int off = 32; off > 0; off >>= 1) m = fmaxf(m, __shfl_down(m, off));
  if ((tid & 63) == 0) red[tid >> 6] = m;
  __syncthreads();
  m = fmaxf(fmaxf(red[0], red[1]), fmaxf(red[2], red[3]));

  float s = 0.f;
  s += (t0 + 0 < cl) ? __expf(v0.x - m) : 0.f;
  s += (t0 + 1 < cl) ? __expf(v0.y - m) : 0.f;
  s += (t0 + 2 < cl) ? __expf(v0.z - m) : 0.f;
  s += (t0 + 3 < cl) ? __expf(v0.w - m) : 0.f;
  s += (t1 + 0 < cl) ? __expf(v1.x - m) : 0.f;
  s += (t1 + 1 < cl) ? __expf(v1.y - m) : 0.f;
  s += (t1 + 2 < cl) ? __expf(v1.z - m) : 0.f;
  s += (t1 + 3 < cl) ? __expf(v1.w - m) : 0.f;
#pragma unroll
  for (int off = 32; off > 0; off >>= 1) s += __shfl_down(s, off);
  if ((tid & 63) == 0) red[4 + (tid >> 6)] = s;
  __syncthreads();
  s = red[4] + red[5] + red[6] + red[7];

  if (tid == 0) {
    m_out[(size_t)b * JJ + j] = m;
    r_out[(size_t)b * JJ + j] = 1.f / s;
  }
}

// ---------------- Kernel C: out[b,t] = sum_{j<qlen} exp(S-m)*r ---------------
__global__ __launch_bounds__(256)
void out_kernel(const float* __restrict__ S, const float* __restrict__ m_arr,
                const float* __restrict__ r_arr, const int* __restrict__ qlen,
                const int* __restrict__ clen, float* __restrict__ out) {
  const int b = blockIdx.y;
  const int t = blockIdx.x * 256 + threadIdx.x;
  const int ql = qlen[b];
  const int cl = clen[b];

  __shared__ float lm[JJ];
  __shared__ float lr[JJ];
  if (threadIdx.x < ql) {
    lm[threadIdx.x] = m_arr[(size_t)b * JJ + threadIdx.x];
    lr[threadIdx.x] = r_arr[(size_t)b * JJ + threadIdx.x];
  }
  __syncthreads();

  float acc = 0.f;
  if (t < cl) {
    const float* col = S + (size_t)b * JJ * TT + t;
#pragma unroll 4
    for (int j = 0; j < ql; j++) {
      acc += __expf(col[(size_t)j * TT] - lm[j]) * lr[j];
    }
  }
  out[(size_t)b * TT + t] = acc;
}

extern "C" void kernel_launch(void* const* d_in, const int* in_sizes, int n_in,
                              void* d_out, int out_size, void* d_ws, size_t ws_size,
                              hipStream_t stream) {
  const float* question = (const float*)d_in[0];  // (B,J,D)
  const float* context  = (const float*)d_in[1];  // (B,T,D)
  const int*   qlen     = (const int*)d_in[2];    // (B,)
  const int*   clen     = (const int*)d_in[3];    // (B,)
  const float* weight   = (const float*)d_in[4];  // (D,1)
  float* out = (float*)d_out;                     // (B,T,1) f32

  // Workspace: S (64 MB) + m (B*J) + r (B*J) + Qhi (8 MB) + Qlo (8 MB)
  float* S = (float*)d_ws;
  float* m_arr = S + (size_t)BB * JJ * TT;
  float* r_arr = m_arr + (size_t)BB * JJ;
  uint4* Qhi = (uint4*)(r_arr + (size_t)BB * JJ);
  uint4* Qlo = Qhi + (size_t)BB * 16 * 512;

  qpack_kernel<<<dim3(2048), 256, 0, stream>>>(question, weight, Qhi, Qlo);
  sim_gemm_mfma<<<dim3(1024), 256, 0, stream>>>(Qhi, Qlo, context, S);
  softmax_stats_kernel<<<dim3(JJ, BB), 256, 0, stream>>>(S, qlen, clen, m_arr, r_arr);
  out_kernel<<<dim3(TT / 256, BB), 256, 0, stream>>>(S, m_arr, r_arr, qlen, clen, out);
}

// Round 2
// 393.627 us; speedup vs baseline: 1.1334x; 1.0562x over previous
//
#include <hip/hip_runtime.h>
#include <stdint.h>
#include <math.h>

// Problem constants (B,T,J,D) = (64, 2048, 128, 512)
#define BB 64
#define TT 2048
#define JJ 128
#define DD 512
#define BK 32    // K chunk per step (one 16x16x32 MFMA K)

typedef short short8 __attribute__((ext_vector_type(8)));
typedef float f32x4 __attribute__((ext_vector_type(4)));

typedef const __attribute__((address_space(1))) uint32_t glb_u32;
typedef __attribute__((address_space(3))) uint32_t lds_u32;

// async global->LDS DMA, 16B per lane; LDS dest = wave-uniform base + lane*16
__device__ __forceinline__ void dma16(const void* g, void* l) {
  __builtin_amdgcn_global_load_lds((glb_u32*)g, (lds_u32*)l, 16, 0, 0);
}

__device__ inline unsigned pk_hi(float a, float b) {
  // (hi16(a)) | (hi16(b) << 16) -- bf16 truncation pack of 2 fp32
  return __builtin_amdgcn_perm(__float_as_uint(b), __float_as_uint(a), 0x07060302u);
}
__device__ inline float truncbf(float x) {
  return __uint_as_float(__float_as_uint(x) & 0xFFFF0000u);
}
// 8 fp32 (two float4) -> hi chunk (8 bf16) + lo chunk (8 bf16)
__device__ inline void pack8(float4 a, float4 b, uint4& h, uint4& l) {
  h = make_uint4(pk_hi(a.x, a.y), pk_hi(a.z, a.w), pk_hi(b.x, b.y), pk_hi(b.z, b.w));
  float l0 = a.x - truncbf(a.x), l1 = a.y - truncbf(a.y);
  float l2 = a.z - truncbf(a.z), l3 = a.w - truncbf(a.w);
  float l4 = b.x - truncbf(b.x), l5 = b.y - truncbf(b.y);
  float l6 = b.z - truncbf(b.z), l7 = b.w - truncbf(b.w);
  l = make_uint4(pk_hi(l0, l1), pk_hi(l2, l3), pk_hi(l4, l5), pk_hi(l6, l7));
}
__device__ inline short8 bc8(uint4 u) { return __builtin_bit_cast(short8, u); }

// ---------------- Kernel A0: pre-pack Q*w into hi/lo bf16 tile images --------
// Qhi/Qlo layout: [b][ks (16)][slot (512 uint4)], slot = j*4 + (c ^ ((j>>1)&3))
// i.e. exactly the byte image the GEMM wants in LDS (swizzle pre-baked).
__global__ __launch_bounds__(256)
void qpack_kernel(const float* __restrict__ Qm, const float* __restrict__ w,
                  uint4* __restrict__ Qhi, uint4* __restrict__ Qlo) {
  const int gid = blockIdx.x * 256 + threadIdx.x;  // 0 .. 524287
  const int c = gid & 3;
  const int ks = (gid >> 2) & 15;
  const int j = (gid >> 6) & 127;
  const int b = gid >> 13;
  const float* qp = Qm + (((size_t)b * JJ + j) * DD) + ks * BK + c * 8;
  const float* wp = w + ks * BK + c * 8;
  float4 a = *(const float4*)qp;
  float4 bq = *(const float4*)(qp + 4);
  float4 wa = *(const float4*)wp;
  float4 wb = *(const float4*)(wp + 4);
  a.x *= wa.x; a.y *= wa.y; a.z *= wa.z; a.w *= wa.w;
  bq.x *= wb.x; bq.y *= wb.y; bq.z *= wb.z; bq.w *= wb.w;
  uint4 h, l;
  pack8(a, bq, h, l);
  const int slot = j * 4 + (c ^ ((j >> 1) & 3));
  const size_t o = ((size_t)(b * 16 + ks)) * 512 + slot;
  Qhi[o] = h;
  Qlo[o] = l;
}

// ---------------- Kernel A: S[b][j][t] = sum_d (Q[b][j][d]*w[d]) * C[b][t][d]
// 128x128 tile, split-bf16 (hi/lo) 3-MFMA scheme, 16 K-steps of 32.
// Dead-work elimination: blocks with t0 >= clen[b] retire immediately (their S
// is never read: softmax denom only involves t<cl, out=0 for t>=cl). MFMA tiles
// and S stores with j-row-tile start >= qlen[b] are skipped (stats/out only
// read j < qlen). Both are bit-exact.
__global__ __launch_bounds__(256, 3)
void sim_gemm_mfma(const uint4* __restrict__ Qhi, const uint4* __restrict__ Qlo,
                   const float* __restrict__ Cm, const int* __restrict__ qlen,
                   const int* __restrict__ clen, float* __restrict__ S) {
  __shared__ uint4 Ah[512];   // 8 KB : 128 rows x 4 chunks (8 bf16 each)
  __shared__ uint4 Al[512];   // 8 KB
  __shared__ uint4 Cl[1024];  // 16 KB: 128 rows x 8 subs (4 fp32 each), swizzled

  // XCD-aware swizzle: 1024 blocks, 8 XCDs -> XCD x gets b in [x*8, x*8+8)
  // so each XCD's L2 only needs 8 b's of Qpk (2 MB < 4 MB).
  const int id = blockIdx.x;
  const int nid = (id & 7) * 128 + (id >> 3);
  const int b = nid >> 4;
  const int t0 = (nid & 15) * 128;

  const int cl = clen[b];
  if (t0 >= cl) return;  // block-uniform: whole tile masked, S never read here
  const int ql = qlen[b];

  const int tid = threadIdx.x;
  const int lane = tid & 63;
  const int wv = tid >> 6;

  // ---- DMA source/dest setup
  // A tile (per ks) = 512 uint4 verbatim from Qhi/Qlo; wave wv covers
  // [wv*128, wv*128+128) uint4 in 2 sweeps of 64.
  const uint4* qh_src = Qhi + (size_t)b * 8192 + wv * 128 + lane;
  const uint4* ql_src = Qlo + (size_t)b * 8192 + wv * 128 + lane;
  char* ah_dst = (char*)Ah + wv * 2048;
  char* al_dst = (char*)Al + wv * 2048;
  // C tile: wave wv covers rows [wv*32, wv*32+32) in 4 sweeps of 8 rows.
  // LDS linear pos (row, sub=lane&7) sources global chunk sub^(row&7);
  // row&7 == (lane>>3)&7 for every sweep.
  const int crow = wv * 32 + (lane >> 3);
  const int cch = (lane & 7) ^ ((lane >> 3) & 7);
  const float* c_src = Cm + ((size_t)b * TT + t0 + crow) * DD + cch * 4;
  char* cl_dst = (char*)Cl + wv * 4096;

  // ---- MFMA fragment assignment: 4 waves in 2x2 over 128x128
  const int wm = (wv & 1) * 64;
  const int wn = (wv >> 1) * 64;
  const int l15 = lane & 15;
  const int q = lane >> 4;
  const int fchunk = q ^ ((l15 >> 1) & 3);
  const int swl = l15 & 7;

  // wave-uniform per-mi row-tile activity (j rows >= ql are never read)
  bool mact[4];
#pragma unroll
  for (int i = 0; i < 4; i++) mact[i] = (wm + i * 16) < ql;
  const bool any_m = mact[0];  // mact is monotone decreasing

  int aslot[4];
#pragma unroll
  for (int i = 0; i < 4; i++) aslot[i] = (wm + i * 16 + l15) * 4 + fchunk;

  f32x4 acc[4][4] = {};

  for (int ks = 0; ks < 16; ks++) {
    __syncthreads();  // previous iter's fragment reads complete
#pragma unroll
    for (int s = 0; s < 2; s++) {
      dma16(qh_src + ks * 512 + s * 64, ah_dst + s * 1024);
      dma16(ql_src + ks * 512 + s * 64, al_dst + s * 1024);
    }
#pragma unroll
    for (int s = 0; s < 4; s++) {
      dma16(c_src + (size_t)ks * BK + s * 8 * DD, cl_dst + s * 1024);
    }
    __syncthreads();  // compiler drains vmcnt(0) before barrier -> tiles visible

    if (!any_m) continue;  // this wave's whole 64-row stripe is beyond ql

    // B fragments: read fp32 from LDS (swizzled subs), convert to hi/lo bf16
    short8 bh[4], bl[4];
#pragma unroll
    for (int ni = 0; ni < 4; ni++) {
      const int row = wn + ni * 16 + l15;
      float4 v0 = __builtin_bit_cast(float4, Cl[row * 8 + ((2 * q) ^ swl)]);
      float4 v1 = __builtin_bit_cast(float4, Cl[row * 8 + ((2 * q + 1) ^ swl)]);
      uint4 h, l;
      pack8(v0, v1, h, l);
      bh[ni] = bc8(h);
      bl[ni] = bc8(l);
    }
#pragma unroll
    for (int mi = 0; mi < 4; mi++) {
      if (!mact[mi]) continue;  // wave-uniform skip: rows never read
      short8 ah = bc8(Ah[aslot[mi]]);
      short8 al = bc8(Al[aslot[mi]]);
#pragma unroll
      for (int ni = 0; ni < 4; ni++) {
        acc[mi][ni] = __builtin_amdgcn_mfma_f32_16x16x32_bf16(ah, bh[ni], acc[mi][ni], 0, 0, 0);
        acc[mi][ni] = __builtin_amdgcn_mfma_f32_16x16x32_bf16(al, bh[ni], acc[mi][ni], 0, 0, 0);
        acc[mi][ni] = __builtin_amdgcn_mfma_f32_16x16x32_bf16(ah, bl[ni], acc[mi][ni], 0, 0, 0);
      }
    }
  }

  // epilogue: C/D layout col=lane&15, row=(lane>>4)*4+reg
#pragma unroll
  for (int mi = 0; mi < 4; mi++) {
    if (!mact[mi]) continue;  // rows >= ql: never read by stats/out
#pragma unroll
    for (int ni = 0; ni < 4; ni++) {
      const int j = wm + mi * 16 + q * 4;
      const int t = t0 + wn + ni * 16 + l15;
      float* dst = S + ((size_t)b * JJ + j) * TT + t;
      dst[0 * TT] = acc[mi][ni][0];
      dst[1 * TT] = acc[mi][ni][1];
      dst[2 * TT] = acc[mi][ni][2];
      dst[3 * TT] = acc[mi][ni][3];
    }
  }
}

// ---------------- Kernel B: per-(b,j) softmax stats over valid t -------------
// Single pass: whole valid 2048-row in registers (8 floats/thread), masked
// max+sum. Loads predicated on t<cl: the tail of S is now unwritten poison.
__global__ __launch_bounds__(256)
void softmax_stats_kernel(const float* __restrict__ S, const int* __restrict__ qlen,
                          const int* __restrict__ clen, float* __restrict__ m_out,
                          float* __restrict__ r_out) {
  const int j = blockIdx.x;
  const int b = blockIdx.y;
  if (j >= qlen[b]) return;
  const int cl = clen[b];
  const int tid = threadIdx.x;
  const float4* row = (const float4*)(S + ((size_t)b * JJ + j) * TT);

  const float NEG = -3.4e38f;
  float4 v0 = make_float4(NEG, NEG, NEG, NEG);
  float4 v1 = make_float4(NEG, NEG, NEG, NEG);
  const int t0 = tid * 4;
  const int t1 = (tid + 256) * 4;
  if (t0 < cl) v0 = row[tid];          // predicated: skip unwritten tail
  if (t1 < cl) v1 = row[tid + 256];

  float m = NEG;
  m = fmaxf(m, (t0 + 0 < cl) ? v0.x : NEG);
  m = fmaxf(m, (t0 + 1 < cl) ? v0.y : NEG);
  m = fmaxf(m, (t0 + 2 < cl) ? v0.z : NEG);
  m = fmaxf(m, (t0 + 3 < cl) ? v0.w : NEG);
  m = fmaxf(m, (t1 + 0 < cl) ? v1.x : NEG);
  m = fmaxf(m, (t1 + 1 < cl) ? v1.y : NEG);
  m = fmaxf(m, (t1 + 2 < cl) ? v1.z : NEG);
  m = fmaxf(m, (t1 + 3 < cl) ? v1.w : NEG);

  __shared__ float red[8];
#pragma unroll
  for (int off = 32; off > 0; off >>= 1) m = fmaxf(m, __shfl_down(m, off));
  if ((tid & 63) == 0) red[tid >> 6] = m;
  __syncthreads();
  m = fmaxf(fmaxf(red[0], red[1]), fmaxf(red[2], red[3]));

  float s = 0.f;
  s += (t0 + 0 < cl) ? __expf(v0.x - m) : 0.f;
  s += (t0 + 1 < cl) ? __expf(v0.y - m) : 0.f;
  s += (t0 + 2 < cl) ? __expf(v0.z - m) : 0.f;
  s += (t0 + 3 < cl) ? __expf(v0.w - m) : 0.f;
  s += (t1 + 0 < cl) ? __expf(v1.x - m) : 0.f;
  s += (t1 + 1 < cl) ? __expf(v1.y - m) : 0.f;
  s += (t1 + 2 < cl) ? __expf(v1.z - m) : 0.f;
  s += (t1 + 3 < cl) ? __expf(v1.w - m) : 0.f;
#pragma unroll
  for (int off = 32; off > 0; off >>= 1) s += __shfl_down(s, off);
  if ((tid & 63) == 0) red[4 + (tid >> 6)] = s;
  __syncthreads();
  s = red[4] + red[5] + red[6] + red[7];

  if (tid == 0) {
    m_out[(size_t)b * JJ + j] = m;
    r_out[(size_t)b * JJ + j] = 1.f / s;
  }
}

// ---------------- Kernel C: out[b,t] = sum_{j<qlen} exp(S-m)*r ---------------
__global__ __launch_bounds__(256)
void out_kernel(const float* __restrict__ S, const float* __restrict__ m_arr,
                const float* __restrict__ r_arr, const int* __restrict__ qlen,
                const int* __restrict__ clen, float* __restrict__ out) {
  const int b = blockIdx.y;
  const int t = blockIdx.x * 256 + threadIdx.x;
  const int ql = qlen[b];
  const int cl = clen[b];

  __shared__ float lm[JJ];
  __shared__ float lr[JJ];
  if (threadIdx.x < ql) {
    lm[threadIdx.x] = m_arr[(size_t)b * JJ + threadIdx.x];
    lr[threadIdx.x] = r_arr[(size_t)b * JJ + threadIdx.x];
  }
  __syncthreads();

  float acc = 0.f;
  if (t < cl) {
    const float* col = S + (size_t)b * JJ * TT + t;
#pragma unroll 4
    for (int j = 0; j < ql; j++) {
      acc += __expf(col[(size_t)j * TT] - lm[j]) * lr[j];
    }
  }
  out[(size_t)b * TT + t] = acc;
}

extern "C" void kernel_launch(void* const* d_in, const int* in_sizes, int n_in,
                              void* d_out, int out_size, void* d_ws, size_t ws_size,
                              hipStream_t stream) {
  const float* question = (const float*)d_in[0];  // (B,J,D)
  const float* context  = (const float*)d_in[1];  // (B,T,D)
  const int*   qlen     = (const int*)d_in[2];    // (B,)
  const int*   clen     = (const int*)d_in[3];    // (B,)
  const float* weight   = (const float*)d_in[4];  // (D,1)
  float* out = (float*)d_out;                     // (B,T,1) f32

  // Workspace: S (64 MB) + m (B*J) + r (B*J) + Qhi (8 MB) + Qlo (8 MB)
  float* S = (float*)d_ws;
  float* m_arr = S + (size_t)BB * JJ * TT;
  float* r_arr = m_arr + (size_t)BB * JJ;
  uint4* Qhi = (uint4*)(r_arr + (size_t)BB * JJ);
  uint4* Qlo = Qhi + (size_t)BB * 16 * 512;

  qpack_kernel<<<dim3(2048), 256, 0, stream>>>(question, weight, Qhi, Qlo);
  sim_gemm_mfma<<<dim3(1024), 256, 0, stream>>>(Qhi, Qlo, context, qlen, clen, S);
  softmax_stats_kernel<<<dim3(JJ, BB), 256, 0, stream>>>(S, qlen, clen, m_arr, r_arr);
  out_kernel<<<dim3(TT / 256, BB), 256, 0, stream>>>(S, m_arr, r_arr, qlen, clen, out);
}